// Round 1
// baseline (4890.410 us; speedup 1.0000x reference)
//
#include <hip/hip_runtime.h>
#include <hip/hip_bf16.h>
#include <cstdint>
#include <cstddef>

#define DEVI __device__ __forceinline__

// ---------- constants ----------
#define BB 128
#define TT 30
#define VOCAB 10000
#define HID 512
#define ENCD 2048
#define NPIX 49

typedef __attribute__((ext_vector_type(8))) short bf16x8;   // 8 bf16 in 4 VGPRs
typedef __attribute__((ext_vector_type(4))) float f32x4;

DEVI float bf2f(unsigned short u){ union{float f; unsigned int i;} x; x.i=((unsigned)u)<<16; return x.f; }
DEVI unsigned short f2bf(float f){ union{float f; unsigned int i;} x; x.f=f; unsigned r=x.i + 0x7fffu + ((x.i>>16)&1u); return (unsigned short)(r>>16); }
DEVI float sigm(float x){ return 1.0f/(1.0f+expf(-x)); }
DEVI f32x4 mfma16(bf16x8 a, bf16x8 b, f32x4 c){ return __builtin_amdgcn_mfma_f32_16x16x32_bf16(a,b,c,0,0,0); }

// ---------- sort: stable descending by length (matches stable argsort of -len) ----------
__global__ void k_sort(const int* __restrict__ lens, int* __restrict__ order, int* __restrict__ Bt){
  __shared__ int L[BB];
  int i = threadIdx.x;
  L[i] = lens[i];
  __syncthreads();
  int li = L[i]; int rank = 0;
  for(int j=0;j<BB;j++){ int lj=L[j]; rank += (lj>li) || (lj==li && j<i); }
  order[rank] = i;
  if(i<TT){ int c=0; for(int j=0;j<BB;j++) c += (L[j]>i); Bt[i]=c; }
}

// ---------- weight f32 -> bf16 conversion ----------
struct WC13 { const float* src[13]; unsigned short* dst[13]; int n[13]; };
__global__ void k_wconv(WC13 wc){
  int stride = gridDim.x*blockDim.x;
  int tid0 = blockIdx.x*blockDim.x + threadIdx.x;
  for(int s=0;s<13;s++){
    const float4* src=(const float4*)wc.src[s];
    int n4 = wc.n[s]>>2;
    ushort4* dst=(ushort4*)wc.dst[s];
    for(int i=tid0;i<n4;i+=stride){
      float4 v=src[i];
      ushort4 o; o.x=f2bf(v.x); o.y=f2bf(v.y); o.z=f2bf(v.z); o.w=f2bf(v.w);
      dst[i]=o;
    }
  }
}

// ---------- xt build: xt[b,t,:] = [emb(cap[order[b],t]) , gimg[b]] in bf16 ----------
__global__ void k_xt(const int* __restrict__ caps, const int* __restrict__ order,
                     const float* __restrict__ embW, const unsigned short* __restrict__ gimg,
                     unsigned short* __restrict__ xt){
  int total=BB*TT*1024;
  for(int idx=blockIdx.x*blockDim.x+threadIdx.x; idx<total; idx+=gridDim.x*blockDim.x){
    int k=idx&1023; int bt=idx>>10; int t=bt%TT; int b=bt/TT;
    unsigned short v;
    if(k<512){ int tok=caps[order[b]*TT+t]; v=f2bf(embW[(size_t)tok*512+k]); }
    else v=gimg[b*512+(k-512)];
    xt[idx]=v;
  }
}

// ---------- GEMM, f32 A with row-reorder (+convert), bf16 W, relu, bf16 out. N=512 ----------
__global__ __launch_bounds__(256) void k_gemm_f32A(
    const float* __restrict__ A, int lda, int rpb, const int* __restrict__ order,
    const unsigned short* __restrict__ W, const float* __restrict__ bias,
    unsigned short* __restrict__ out, int K)
{
  __shared__ unsigned short As[128][136];
  int tid=threadIdx.x, wave=tid>>6, lane=tid&63, l15=lane&15, l4=lane>>4;
  int mb = blockIdx.y*128;
  f32x4 acc[8];
  f32x4 z = {0.f,0.f,0.f,0.f};
  #pragma unroll
  for(int i=0;i<8;i++) acc[i]=z;
  int cch=tid&15, r0=tid>>4;
  int nrow = blockIdx.x*64 + wave*16 + l15;
  for(int kc=0;kc<K;kc+=128){
    __syncthreads();
    #pragma unroll
    for(int rp=0;rp<8;rp++){
      int r=r0+rp*16;
      int m=mb+r;
      int sb = order[m/rpb]*rpb + m%rpb;
      const float* p = A + (size_t)sb*lda + kc + cch*8;
      float4 v0=*(const float4*)p, v1=*(const float4*)(p+4);
      unsigned short* d=&As[r][cch*8];
      d[0]=f2bf(v0.x); d[1]=f2bf(v0.y); d[2]=f2bf(v0.z); d[3]=f2bf(v0.w);
      d[4]=f2bf(v1.x); d[5]=f2bf(v1.y); d[6]=f2bf(v1.z); d[7]=f2bf(v1.w);
    }
    __syncthreads();
    #pragma unroll
    for(int kk=0;kk<4;kk++){
      bf16x8 bfr = *(const bf16x8*)(W + (size_t)nrow*K + kc + kk*32 + l4*8);
      #pragma unroll
      for(int mt=0;mt<8;mt++){
        bf16x8 af = *(const bf16x8*)&As[mt*16+l15][kk*32+l4*8];
        acc[mt]=mfma16(af,bfr,acc[mt]);
      }
    }
  }
  int n = blockIdx.x*64 + wave*16 + l15;
  float bs = bias[n];
  #pragma unroll
  for(int mt=0;mt<8;mt++){
    #pragma unroll
    for(int j=0;j<4;j++){
      int row = mb + mt*16 + l4*4 + j;
      float v = acc[mt][j]+bs; v = v>0.f ? v : 0.f;
      out[(size_t)row*512 + n] = f2bf(v);
    }
  }
}

// ---------- generic multi-GEMM: bf16 A (ld 512), bf16 W (512x512), M=128*gridDim.y ----------
struct GDesc { const unsigned short* A; const unsigned short* W; const float* bias; void* out; int act; int outbf; };
struct GDesc6 { GDesc d[6]; };
__global__ __launch_bounds__(256) void k_gemm512(GDesc6 dd){
  GDesc g = dd.d[blockIdx.z];
  __shared__ unsigned short As[128][136];
  int tid=threadIdx.x, wave=tid>>6, lane=tid&63, l15=lane&15, l4=lane>>4;
  int mb=blockIdx.y*128;
  f32x4 acc[8];
  f32x4 z = {0.f,0.f,0.f,0.f};
  #pragma unroll
  for(int i=0;i<8;i++) acc[i]=z;
  int cch=tid&15, r0=tid>>4;
  int nrow = blockIdx.x*64 + wave*16 + l15;
  for(int kc=0;kc<512;kc+=128){
    __syncthreads();
    #pragma unroll
    for(int rp=0;rp<8;rp++){
      int r=r0+rp*16;
      *(uint4*)&As[r][cch*8] = *(const uint4*)(g.A + (size_t)(mb+r)*512 + kc + cch*8);
    }
    __syncthreads();
    #pragma unroll
    for(int kk=0;kk<4;kk++){
      bf16x8 bfr = *(const bf16x8*)(g.W + (size_t)nrow*512 + kc + kk*32 + l4*8);
      #pragma unroll
      for(int mt=0;mt<8;mt++){
        bf16x8 af = *(const bf16x8*)&As[mt*16+l15][kk*32+l4*8];
        acc[mt]=mfma16(af,bfr,acc[mt]);
      }
    }
  }
  int n = blockIdx.x*64 + wave*16 + l15;
  float bs = g.bias ? g.bias[n] : 0.f;
  #pragma unroll
  for(int mt=0;mt<8;mt++){
    #pragma unroll
    for(int j=0;j<4;j++){
      int row = mb + mt*16 + l4*4 + j;
      float v = acc[mt][j]+bs;
      if(g.act==1) v = fmaxf(v,0.f);
      else if(g.act==2) v = tanhf(v);
      size_t idx=(size_t)row*512+n;
      if(g.outbf) ((unsigned short*)g.out)[idx]=f2bf(v);
      else ((float*)g.out)[idx]=v;
    }
  }
}

// ---------- fused LSTM step: gates + sentinel-gate GEMMs + elementwise ----------
// A = [xt_t (1024) | h_old (512)], strips: i,f,g,o (Wih/Whh rows s*512+j) and s-gate (xg/hg row j)
__global__ __launch_bounds__(256) void k_lstm(
  const unsigned short* __restrict__ xt, int t,
  const unsigned short* __restrict__ hold, unsigned short* __restrict__ hnew,
  float* __restrict__ c, unsigned short* __restrict__ st,
  const unsigned short* __restrict__ Wih, const unsigned short* __restrict__ Whh,
  const unsigned short* __restrict__ Wxg, const unsigned short* __restrict__ Whg,
  const float* __restrict__ bih, const float* __restrict__ bhh,
  const float* __restrict__ bxg, const float* __restrict__ bhg,
  const int* __restrict__ Bt)
{
  __shared__ unsigned short As[128][136];
  int tid=threadIdx.x, wave=tid>>6, lane=tid&63, l15=lane&15, l4=lane>>4;
  int jb = blockIdx.x*16;
  f32x4 acc[2][5];
  f32x4 z = {0.f,0.f,0.f,0.f};
  #pragma unroll
  for(int m=0;m<2;m++)
    #pragma unroll
    for(int s=0;s<5;s++) acc[m][s]=z;
  int cch=tid&15, r0=tid>>4;
  for(int kc=0;kc<1536;kc+=128){
    __syncthreads();
    #pragma unroll
    for(int rp=0;rp<8;rp++){
      int r=r0+rp*16;
      int kg = kc + cch*8;
      const unsigned short* src;
      if(kg<1024) src = xt + (size_t)r*(TT*1024) + t*1024 + kg;
      else        src = hold + (size_t)r*512 + (kg-1024);
      *(uint4*)&As[r][cch*8] = *(const uint4*)src;
    }
    __syncthreads();
    #pragma unroll
    for(int kk=0;kk<4;kk++){
      int kg = kc + kk*32 + l4*8;
      bf16x8 bfr[5];
      #pragma unroll
      for(int s=0;s<5;s++){
        int row = (s<4) ? (s*512 + jb + l15) : (jb + l15);
        const unsigned short* wp;
        if(s<4) wp = (kg<1024) ? (Wih + (size_t)row*1024 + kg) : (Whh + (size_t)row*512 + (kg-1024));
        else    wp = (kg<1024) ? (Wxg + (size_t)row*1024 + kg) : (Whg + (size_t)row*512 + (kg-1024));
        bfr[s] = *(const bf16x8*)wp;
      }
      #pragma unroll
      for(int m=0;m<2;m++){
        int mt = wave*2+m;
        bf16x8 af = *(const bf16x8*)&As[mt*16+l15][kk*32+l4*8];
        #pragma unroll
        for(int s=0;s<5;s++) acc[m][s]=mfma16(af,bfr[s],acc[m][s]);
      }
    }
  }
  int bt = Bt[t];
  int j = jb + l15;
  float bi  = bih[j]      + bhh[j];
  float bff = bih[512+j]  + bhh[512+j];
  float bg  = bih[1024+j] + bhh[1024+j];
  float bo  = bih[1536+j] + bhh[1536+j];
  float bs  = bxg[j] + bhg[j];
  #pragma unroll
  for(int m=0;m<2;m++){
    int mt = wave*2+m;
    #pragma unroll
    for(int jj=0;jj<4;jj++){
      int b = mt*16 + l4*4 + jj;
      float iv = sigm(acc[m][0][jj]+bi);
      float fv = sigm(acc[m][1][jj]+bff);
      float gv = tanhf(acc[m][2][jj]+bg);
      float ov = sigm(acc[m][3][jj]+bo);
      float sv = sigm(acc[m][4][jj]+bs);
      float cold = (t==0) ? 0.f : c[(size_t)b*512+j];
      float cn = fv*cold + iv*gv;
      float tc = tanhf(cn);
      float hn = ov*tc;
      float stv = sv*tc;
      size_t idx=(size_t)b*512+j;
      if(b<bt){ hnew[idx]=f2bf(hn); c[idx]=cn; }
      else    { hnew[idx]=hold[idx]; }            // carry old h; c untouched
      st[idx]=f2bf(stv);
    }
  }
}

// ---------- attention: scores -> softmax(50) -> out_l = tanh(sum_p a_p*SC + a49*scs + sch + ctx_b) ----------
__global__ __launch_bounds__(256) void k_attn(
  const unsigned short* __restrict__ vattn, const float* __restrict__ satt,
  const float* __restrict__ hatt, const float* __restrict__ alW, const float* __restrict__ alb,
  const float* __restrict__ scs, const float* __restrict__ sch, const float* __restrict__ ctxb,
  const unsigned short* __restrict__ SC, unsigned short* __restrict__ outl)
{
  int b = blockIdx.x;
  __shared__ float sS[52];
  __shared__ float sA[52];
  int tid=threadIdx.x; int gid=tid>>4, gl=tid&15;
  const float* ha = hatt + (size_t)b*512;
  #pragma unroll
  for(int rp=0;rp<4;rp++){
    int p = rp*16 + gid;
    float s = 0.f;
    if(p<50){
      if(p<NPIX){
        const unsigned short* vp = vattn + ((size_t)b*NPIX + p)*512;
        for(int k=gl*32;k<gl*32+32;k++) s += tanhf(bf2f(vp[k]) + ha[k]) * alW[k];
      } else {
        const float* sa = satt + (size_t)b*512;
        for(int k=gl*32;k<gl*32+32;k++) s += tanhf(sa[k] + ha[k]) * alW[k];
      }
    }
    #pragma unroll
    for(int off=8;off>=1;off>>=1) s += __shfl_xor(s, off);
    if(gl==0 && p<50) sS[p] = s + alb[0];
  }
  __syncthreads();
  if(tid==0){
    float m=-1e30f;
    for(int p=0;p<50;p++) m = fmaxf(m, sS[p]);
    float sum=0.f;
    for(int p=0;p<50;p++){ float e=expf(sS[p]-m); sA[p]=e; sum+=e; }
    float inv=1.f/sum;
    for(int p=0;p<50;p++) sA[p]*=inv;
  }
  __syncthreads();
  float a49 = sA[49];
  for(int n=tid;n<512;n+=256){
    float acc = sch[(size_t)b*512+n] + a49*scs[(size_t)b*512+n] + ctxb[n];
    const unsigned short* sp = SC + (size_t)b*NPIX*512 + n;
    for(int p=0;p<NPIX;p++) acc += sA[p]*bf2f(sp[(size_t)p*512]);
    outl[(size_t)b*512+n] = f2bf(tanhf(acc));
  }
}

// ---------- fc: logits, masked-zero for inactive rows ----------
__global__ __launch_bounds__(256) void k_fc(
  const unsigned short* __restrict__ outl, const unsigned short* __restrict__ W,
  const float* __restrict__ bias, float* __restrict__ dout, int t, const int* __restrict__ Bt)
{
  __shared__ unsigned short As[128][136];
  int tid=threadIdx.x, wave=tid>>6, lane=tid&63, l15=lane&15, l4=lane>>4;
  int bt = Bt[t];
  f32x4 acc[8];
  f32x4 z = {0.f,0.f,0.f,0.f};
  #pragma unroll
  for(int i=0;i<8;i++) acc[i]=z;
  int cch=tid&15, r0=tid>>4;
  int nbase = blockIdx.x*64 + wave*16;
  int nr = nbase + l15; if(nr > VOCAB-1) nr = VOCAB-1;
  for(int kc=0;kc<512;kc+=128){
    __syncthreads();
    #pragma unroll
    for(int rp=0;rp<8;rp++){
      int r=r0+rp*16;
      *(uint4*)&As[r][cch*8] = *(const uint4*)(outl + (size_t)r*512 + kc + cch*8);
    }
    __syncthreads();
    #pragma unroll
    for(int kk=0;kk<4;kk++){
      bf16x8 bfr = *(const bf16x8*)(W + (size_t)nr*512 + kc + kk*32 + l4*8);
      #pragma unroll
      for(int mt=0;mt<8;mt++){
        if(mt*16 < bt){
          bf16x8 af = *(const bf16x8*)&As[mt*16+l15][kk*32+l4*8];
          acc[mt]=mfma16(af,bfr,acc[mt]);
        }
      }
    }
  }
  int n = nbase + l15; bool nok = n < VOCAB;
  float bs = nok ? bias[n] : 0.f;
  #pragma unroll
  for(int mt=0;mt<8;mt++){
    #pragma unroll
    for(int j=0;j<4;j++){
      int b = mt*16 + l4*4 + j;
      float v = (b<bt) ? (acc[mt][j]+bs) : 0.f;
      if(nok) dout[(size_t)b*(TT*VOCAB) + (size_t)t*VOCAB + n] = v;
    }
  }
}

// ---------- host launch ----------
extern "C" void kernel_launch(void* const* d_in, const int* in_sizes, int n_in,
                              void* d_out, int out_size, void* d_ws, size_t ws_size,
                              hipStream_t stream)
{
  const float* enc  =(const float*)d_in[0];
  const float* gfeat=(const float*)d_in[1];
  const int*   caps =(const int*)d_in[2];
  const int*   lens =(const int*)d_in[3];
  const float* embW =(const float*)d_in[4];
  const float* e2hW =(const float*)d_in[5];  const float* e2hb=(const float*)d_in[6];
  const float* gfW  =(const float*)d_in[7];  const float* gfb =(const float*)d_in[8];
  const float* fcW  =(const float*)d_in[9];  const float* fcb =(const float*)d_in[10];
  const float* WihF =(const float*)d_in[11]; const float* bih =(const float*)d_in[12];
  const float* WhhF =(const float*)d_in[13]; const float* bhh =(const float*)d_in[14];
  const float* xgWF =(const float*)d_in[15]; const float* bxg =(const float*)d_in[16];
  const float* hgWF =(const float*)d_in[17]; const float* bhg =(const float*)d_in[18];
  const float* saWF =(const float*)d_in[19]; const float* sab =(const float*)d_in[20];
  const float* stWF =(const float*)d_in[21]; const float* stbias=(const float*)d_in[22];
  const float* haWF =(const float*)d_in[23]; const float* hab =(const float*)d_in[24];
  const float* htWF =(const float*)d_in[25]; const float* htb =(const float*)d_in[26];
  const float* vaWF =(const float*)d_in[27]; const float* vab =(const float*)d_in[28];
  const float* alW  =(const float*)d_in[29]; const float* alb =(const float*)d_in[30];
  const float* cxWF =(const float*)d_in[31]; const float* cxb =(const float*)d_in[32];

  char* base=(char*)d_ws; size_t off=0;
  auto alloc=[&](size_t bytes)->void*{ void* r=base+off; off += (bytes+255)&~(size_t)255; return r; };

  int* order=(int*)alloc(BB*4);
  int* Bt   =(int*)alloc(32*4);
  unsigned short* w_e2h =(unsigned short*)alloc((size_t)512*2048*2);
  unsigned short* w_gf  =(unsigned short*)alloc((size_t)512*2048*2);
  unsigned short* w_fc  =(unsigned short*)alloc((size_t)VOCAB*512*2);
  unsigned short* w_ih  =(unsigned short*)alloc((size_t)2048*1024*2);
  unsigned short* w_hh  =(unsigned short*)alloc((size_t)2048*512*2);
  unsigned short* w_xg  =(unsigned short*)alloc((size_t)512*1024*2);
  unsigned short* w_hg  =(unsigned short*)alloc((size_t)512*512*2);
  unsigned short* w_saff=(unsigned short*)alloc((size_t)512*512*2);
  unsigned short* w_satt=(unsigned short*)alloc((size_t)512*512*2);
  unsigned short* w_haff=(unsigned short*)alloc((size_t)512*512*2);
  unsigned short* w_hatt=(unsigned short*)alloc((size_t)512*512*2);
  unsigned short* w_vatt=(unsigned short*)alloc((size_t)512*512*2);
  unsigned short* w_ctx =(unsigned short*)alloc((size_t)512*512*2);
  unsigned short* spatial=(unsigned short*)alloc((size_t)BB*NPIX*512*2);
  unsigned short* vattn  =(unsigned short*)alloc((size_t)BB*NPIX*512*2);
  unsigned short* SC     =(unsigned short*)alloc((size_t)BB*NPIX*512*2);
  unsigned short* gimg   =(unsigned short*)alloc((size_t)BB*512*2);
  unsigned short* xt     =(unsigned short*)alloc((size_t)BB*TT*1024*2);
  unsigned short* hbuf0  =(unsigned short*)alloc((size_t)BB*512*2);
  unsigned short* hbuf1  =(unsigned short*)alloc((size_t)BB*512*2);
  float* cbuf =(float*)alloc((size_t)BB*512*4);
  unsigned short* stb_buf=(unsigned short*)alloc((size_t)BB*512*2);
  unsigned short* saff   =(unsigned short*)alloc((size_t)BB*512*2);
  unsigned short* haff   =(unsigned short*)alloc((size_t)BB*512*2);
  float* satt=(float*)alloc((size_t)BB*512*4);
  float* hatt=(float*)alloc((size_t)BB*512*4);
  float* scs =(float*)alloc((size_t)BB*512*4);
  float* sch =(float*)alloc((size_t)BB*512*4);
  unsigned short* outl=(unsigned short*)alloc((size_t)BB*512*2);

  k_sort<<<1,BB,0,stream>>>(lens, order, Bt);

  WC13 wc;
  const float* srcs[13] = {e2hW,gfW,fcW,WihF,WhhF,xgWF,hgWF,saWF,stWF,haWF,htWF,vaWF,cxWF};
  unsigned short* dsts[13] = {w_e2h,w_gf,w_fc,w_ih,w_hh,w_xg,w_hg,w_saff,w_satt,w_haff,w_hatt,w_vatt,w_ctx};
  int ns[13] = {512*2048,512*2048,VOCAB*512,2048*1024,2048*512,512*1024,512*512,512*512,512*512,512*512,512*512,512*512,512*512};
  for(int i=0;i<13;i++){ wc.src[i]=srcs[i]; wc.dst[i]=dsts[i]; wc.n[i]=ns[i]; }
  k_wconv<<<1024,256,0,stream>>>(wc);

  hipMemsetAsync(hbuf0, 0, (size_t)BB*512*2, stream);

  // spatial = relu(enc[order] @ e2h^T + b), gimg = relu(gf[order] @ gf_W^T + b)
  k_gemm_f32A<<<dim3(8,NPIX),256,0,stream>>>(enc, ENCD, NPIX, order, w_e2h, e2hb, spatial, ENCD);
  k_gemm_f32A<<<dim3(8,1),  256,0,stream>>>(gfeat, ENCD, 1, order, w_gf, gfb, gimg, ENCD);
  k_xt<<<1024,256,0,stream>>>(caps, order, embW, gimg, xt);

  {
    GDesc6 dv{};
    dv.d[0] = GDesc{spatial, w_vatt, vab,     vattn, 0, 1};
    dv.d[1] = GDesc{spatial, w_ctx,  nullptr, SC,    0, 1};
    k_gemm512<<<dim3(8,NPIX,2),256,0,stream>>>(dv);
  }

  for(int t=0;t<TT;t++){
    unsigned short* hold = (t&1) ? hbuf1 : hbuf0;
    unsigned short* hnew = (t&1) ? hbuf0 : hbuf1;
    k_lstm<<<32,256,0,stream>>>(xt, t, hold, hnew, cbuf, stb_buf,
                                w_ih, w_hh, w_xg, w_hg, bih, bhh, bxg, bhg, Bt);
    {
      GDesc6 d2{};
      d2.d[0] = GDesc{stb_buf, w_saff, sab, saff, 1, 1};
      d2.d[1] = GDesc{hnew,    w_haff, hab, haff, 2, 1};
      k_gemm512<<<dim3(8,1,2),256,0,stream>>>(d2);
    }
    {
      GDesc6 d4{};
      d4.d[0] = GDesc{saff, w_satt, stbias,  satt, 0, 0};
      d4.d[1] = GDesc{haff, w_hatt, htb,     hatt, 0, 0};
      d4.d[2] = GDesc{saff, w_ctx,  nullptr, scs,  0, 0};
      d4.d[3] = GDesc{haff, w_ctx,  nullptr, sch,  0, 0};
      k_gemm512<<<dim3(8,1,4),256,0,stream>>>(d4);
    }
    k_attn<<<BB,256,0,stream>>>(vattn, satt, hatt, alW, alb, scs, sch, cxb, SC, outl);
    k_fc<<<157,256,0,stream>>>(outl, w_fc, fcb, (float*)d_out, t, Bt);
  }
}